// Round 5
// baseline (48.671 us; speedup 1.0000x reference)
//
#include <hip/hip_runtime.h>

// Fused FAC (per-pixel 3x3 convolution with residual):
// out[n,c,h,w] = feat[n,c,h,w] + sum_{i,j} feat_pad[n,c,h+i,w+j] * att[n,i*3+j,h,w]
// feature: [8,64,256,256] f32, attention: [8,9,256,256] f32, out: [8,64,256,256] f32.
//
// Round-4 (48us): LDS-resident pipeline via global_load_lds (no dest VGPRs ->
// regalloc can't sink it), 3-deep ring, raw s_barrier + COUNTED vmcnt.
// Round-5: (a) stage exactly 6 rows/channel instead of 8 (slots 6,7 were
// padding -> 25% wasted staging traffic); waves 0,1 stage 2 rows, waves 2,3
// stage 1 row, with role-dependent counted vmcnt. (b) LDS 25.6->19.0 KB and
// __launch_bounds__(256,6) for ~24 waves/CU (was 16) to smooth barrier stalls.

constexpr int N_ = 8, C_ = 64, H_ = 256, W_ = 256;
constexpr int ROWS = 4;                 // output rows per block (1 per wave)
constexpr int CG = 4;                   // channel groups (blocks per pixel tile)
constexpr int CPG = C_ / CG;            // 16 channels per block
constexpr int HB = H_ / ROWS;           // 64 row tiles
constexpr int NWG = N_ * HB * CG;       // 2048 blocks
constexpr int NXCD = 8;
constexpr int NBUF = 3;                 // LDS ring depth (prefetch 2 channels ahead)
constexpr int SLOTS = 6;                // rows staged per channel: h0-1 .. h0+4
constexpr int BUFF = SLOTS * W_;        // floats per ring buffer = 1536

using f32x4 = __attribute__((ext_vector_type(4))) float;

__global__ __launch_bounds__(256, 6) void fac_kernel(
    const float* __restrict__ feat, const float* __restrict__ att,
    float* __restrict__ out) {
  __shared__ float smem[NBUF * BUFF + W_];   // ring + 1 zero row (19456 B)
  constexpr int ZROW = NBUF * BUFF;

  // XCD-aware bijective swizzle (NWG % 8 == 0).
  int bid = blockIdx.x;
  int lg = (bid % NXCD) * (NWG / NXCD) + bid / NXCD;
  int cg = lg % CG;
  int hb = (lg / CG) % HB;
  int n  = lg / (CG * HB);

  int tx = threadIdx.x & 63;   // lane: w4 = tx*4 (wave spans full W row)
  int rt = threadIdx.x >> 6;   // wave id = output row within tile
  int h0 = hb * ROWS;
  int h  = h0 + rt;
  int w4 = tx << 2;

  const size_t plane = (size_t)H_ * W_;

  // Zero row: read in place of the OOB h-1 / h+1 row at image top/bottom.
  smem[ZROW + threadIdx.x] = 0.f;            // 256 threads x 4 B

  // Attention taps in registers (AGPR-parked is fine), reused across CPG channels.
  const float* attp = att + ((size_t)n * 9 * H_ + h) * (size_t)W_ + w4;
  float4 a[9];
#pragma unroll
  for (int t = 0; t < 9; ++t) a[t] = *(const float4*)(attp + (size_t)t * plane);
#pragma unroll
  for (int t = 0; t < 9; ++t)                // keep-alive: forbid remat
    asm volatile("" : "+v"(a[t].x), "+v"(a[t].y), "+v"(a[t].z), "+v"(a[t].w));

  const float* fbase = feat + ((size_t)n * C_ + (size_t)cg * CPG) * plane;
  float* obase = out + ((size_t)n * C_ + (size_t)cg * CPG) * plane
                     + (size_t)h * W_ + w4;

  // Staging roles: 6 row-slots, slot s <-> global row clamp(h0-1+s).
  // waves 0,1 stage slots {0,1},{2,3}; waves 2,3 stage slots {4},{5}.
  const bool two = (rt < 2);                 // wave-uniform role
  const int sA = two ? rt * 2 : rt + 2;
  const int sB = rt * 2 + 1;                 // valid only when two
  const int grA = min(max(h0 - 1 + sA, 0), H_ - 1);
  const int grB = min(max(h0 - 1 + sB, 0), H_ - 1);
  const float* srcA = fbase + (size_t)grA * W_ + w4;   // +lane*16B
  const float* srcB = fbase + (size_t)grB * W_ + w4;

  auto STAGE = [&](int ch, int buf) {
    // LDS dest is wave-uniform base + lane*16 (linear); global src is per-lane.
    __builtin_amdgcn_global_load_lds(
        (const __attribute__((address_space(1))) uint32_t*)(srcA + (size_t)ch * plane),
        (__attribute__((address_space(3))) uint32_t*)&smem[buf * BUFF + sA * W_],
        16, 0, 0);
    if (two)
      __builtin_amdgcn_global_load_lds(
          (const __attribute__((address_space(1))) uint32_t*)(srcB + (size_t)ch * plane),
          (__attribute__((address_space(3))) uint32_t*)&smem[buf * BUFF + sB * W_],
          16, 0, 0);
  };

  const bool hasUp = (h > 0);        // wave-uniform
  const bool hasDn = (h < H_ - 1);   // wave-uniform

  STAGE(0, 0);
  STAGE(1, 1);

#pragma unroll
  for (int c = 0; c < CPG; ++c) {
    // Counted waits (per-wave, role-dependent): drain own stage(c) loads,
    // keep stage(c+1) [k ops] + last store in flight, THEN barrier.
    if (c == 0) {
      if (two) asm volatile("s_waitcnt vmcnt(2) lgkmcnt(0)\n\ts_barrier" ::: "memory");
      else     asm volatile("s_waitcnt vmcnt(1) lgkmcnt(0)\n\ts_barrier" ::: "memory");
    } else if (c == CPG - 1) {
      asm volatile("s_waitcnt vmcnt(2)\n\ts_barrier" ::: "memory");
    } else {
      if (two) asm volatile("s_waitcnt vmcnt(3)\n\ts_barrier" ::: "memory");
      else     asm volatile("s_waitcnt vmcnt(2)\n\ts_barrier" ::: "memory");
    }

    // Prefetch 2 channels ahead into the ring slot freed at iter c-1.
    if (c + 2 < CPG) STAGE(c + 2, (c + 2) % NBUF);

    const int bb = (c % NBUF) * BUFF;
    const float* rA = &smem[hasUp ? bb + rt * W_ : ZROW] + w4;        // row h-1
    const float* rB = &smem[bb + (rt + 1) * W_] + w4;                 // row h
    const float* rC = &smem[hasDn ? bb + (rt + 2) * W_ : ZROW] + w4;  // row h+1

    float4 f0 = *(const float4*)rA;
    float4 f1 = *(const float4*)rB;
    float4 f2 = *(const float4*)rC;

    // w-halos via wave shuffles (wave spans the full row; lane edges = image edges)
    float l0 = __shfl_up(f0.w, 1),  l1 = __shfl_up(f1.w, 1),  l2 = __shfl_up(f2.w, 1);
    float r0 = __shfl_down(f0.x, 1), r1 = __shfl_down(f1.x, 1), r2 = __shfl_down(f2.x, 1);
    if (tx == 0)  { l0 = 0.f; l1 = 0.f; l2 = 0.f; }
    if (tx == 63) { r0 = 0.f; r1 = 0.f; r2 = 0.f; }

    float4 acc = f1;                     // residual: out = feat + FAC
    acc.x += l0   * a[0].x + f0.x * a[1].x + f0.y * a[2].x;
    acc.y += f0.x * a[0].y + f0.y * a[1].y + f0.z * a[2].y;
    acc.z += f0.y * a[0].z + f0.z * a[1].z + f0.w * a[2].z;
    acc.w += f0.z * a[0].w + f0.w * a[1].w + r0   * a[2].w;

    acc.x += l1   * a[3].x + f1.x * a[4].x + f1.y * a[5].x;
    acc.y += f1.x * a[3].y + f1.y * a[4].y + f1.z * a[5].y;
    acc.z += f1.y * a[3].z + f1.z * a[4].z + f1.w * a[5].z;
    acc.w += f1.z * a[3].w + f1.w * a[4].w + r1   * a[5].w;

    acc.x += l2   * a[6].x + f2.x * a[7].x + f2.y * a[8].x;
    acc.y += f2.x * a[6].y + f2.y * a[7].y + f2.z * a[8].y;
    acc.z += f2.y * a[6].z + f2.z * a[7].z + f2.w * a[8].z;
    acc.w += f2.z * a[6].w + f2.w * a[7].w + r2   * a[8].w;

    // Output is never re-read: nontemporal store keeps L2 for the inputs.
    f32x4 accv = {acc.x, acc.y, acc.z, acc.w};
    __builtin_nontemporal_store(accv, (f32x4*)(obase + (size_t)c * plane));
  }
}

extern "C" void kernel_launch(void* const* d_in, const int* in_sizes, int n_in,
                              void* d_out, int out_size, void* d_ws, size_t ws_size,
                              hipStream_t stream) {
  const float* feat = (const float*)d_in[0];
  const float* att  = (const float*)d_in[1];
  float* out        = (float*)d_out;
  fac_kernel<<<NWG, 256, 0, stream>>>(feat, att, out);
}

// Round 6
// 45.697 us; speedup vs baseline: 1.0651x; 1.0651x over previous
//
#include <hip/hip_runtime.h>

// Fused FAC (per-pixel 3x3 convolution with residual):
// out[n,c,h,w] = feat[n,c,h,w] + sum_{i,j} feat_pad[n,c,h+i,w+j] * att[n,i*3+j,h,w]
// feature: [8,64,256,256] f32, attention: [8,9,256,256] f32, out: [8,64,256,256] f32.
//
// Round-6: rounds 4-5 (48us, 4.36 TB/s effective) used a shared LDS slab ->
// 16 s_barrier rendezvous per block; slowest wave's HBM-latency tail gated
// all 4 waves each iteration (VALUBusy 13%, occ 52%). This round: WAVE-PRIVATE
// staging -- each wave global_load_lds's exactly the 3 rows it reads into its
// own LDS ring and self-syncs with counted vmcnt. ZERO barriers. 3x L2-side
// feature reads (L3-absorbed, not HBM); LDS 37.9KB -> 4 blocks/CU, grid 1024
// all co-resident.

constexpr int N_ = 8, C_ = 64, H_ = 256, W_ = 256;
constexpr int ROWS = 4;                 // output rows per block (1 per wave)
constexpr int CG = 2;                   // channel groups (blocks per pixel tile)
constexpr int CPG = C_ / CG;            // 32 channels per block
constexpr int HB = H_ / ROWS;           // 64 row tiles
constexpr int NWG = N_ * HB * CG;       // 1024 blocks
constexpr int NXCD = 8;
constexpr int NBUF = 3;                 // LDS ring depth (prefetch 2 channels ahead)
constexpr int WROWS = 3;                // rows staged per wave per channel
constexpr int BUFW = ROWS * WROWS * W_; // floats per ring buffer = 3072
constexpr int ZROW = NBUF * BUFW;       // zero-row offset (floats) = 9216

using f32x4 = __attribute__((ext_vector_type(4))) float;

__global__ __launch_bounds__(256, 4) void fac_kernel(
    const float* __restrict__ feat, const float* __restrict__ att,
    float* __restrict__ out) {
  __shared__ float smem[NBUF * BUFW + W_];   // ring + 1 zero row = 37888 B

  // XCD-aware bijective swizzle (NWG % 8 == 0): XCD k owns image n=k.
  int bid = blockIdx.x;
  int lg = (bid % NXCD) * (NWG / NXCD) + bid / NXCD;
  int cg = lg % CG;
  int hb = (lg / CG) % HB;
  int n  = lg / (CG * HB);

  int tx = threadIdx.x & 63;   // lane: w4 = tx*4 (wave spans full W row)
  int rt = threadIdx.x >> 6;   // wave id = output row within tile
  int h0 = hb * ROWS;
  int h  = h0 + rt;
  int w4 = tx << 2;

  const size_t plane = (size_t)H_ * W_;

  // Zero row (read in place of OOB h+-1 rows at image top/bottom). Every
  // wave writes the whole row itself (identical-value race is benign) so
  // its later reads are self-ordered -- no cross-wave dependency, no barrier.
  {
    f32x4 z = {0.f, 0.f, 0.f, 0.f};
    *(f32x4*)&smem[ZROW + w4] = z;
  }

  // Attention taps in registers, reused across all CPG channels.
  const float* attp = att + ((size_t)n * 9 * H_ + h) * (size_t)W_ + w4;
  float4 a[9];
#pragma unroll
  for (int t = 0; t < 9; ++t) a[t] = *(const float4*)(attp + (size_t)t * plane);
#pragma unroll
  for (int t = 0; t < 9; ++t)                // keep-alive: forbid remat; also
    asm volatile("" : "+v"(a[t].x), "+v"(a[t].y), "+v"(a[t].z), "+v"(a[t].w));
  // (forces att loads drained before the loop => our vmcnt counts are exact)

  const float* fbase = feat + ((size_t)n * C_ + (size_t)cg * CPG) * plane;
  float* obase = out + ((size_t)n * C_ + (size_t)cg * CPG) * plane
                     + (size_t)h * W_ + w4;

  // Wave-private staging: 3 source rows (clamped at edges; clamped row lands
  // in a slot that compute replaces with the zero row).
  const int g0 = max(h - 1, 0), g2 = min(h + 1, H_ - 1);
  const float* src0 = fbase + (size_t)g0 * W_ + w4;   // +lane*16B
  const float* src1 = fbase + (size_t)h  * W_ + w4;
  const float* src2 = fbase + (size_t)g2 * W_ + w4;
  const int wb = rt * WROWS * W_;            // this wave's region (floats)

  auto STAGE = [&](int ch, int buf) {
    const int b = buf * BUFW + wb;
    __builtin_amdgcn_global_load_lds(
        (const __attribute__((address_space(1))) uint32_t*)(src0 + (size_t)ch * plane),
        (__attribute__((address_space(3))) uint32_t*)&smem[b], 16, 0, 0);
    __builtin_amdgcn_global_load_lds(
        (const __attribute__((address_space(1))) uint32_t*)(src1 + (size_t)ch * plane),
        (__attribute__((address_space(3))) uint32_t*)&smem[b + W_], 16, 0, 0);
    __builtin_amdgcn_global_load_lds(
        (const __attribute__((address_space(1))) uint32_t*)(src2 + (size_t)ch * plane),
        (__attribute__((address_space(3))) uint32_t*)&smem[b + 2 * W_], 16, 0, 0);
  };

  const bool hasUp = (h > 0);        // wave-uniform
  const bool hasDn = (h < H_ - 1);   // wave-uniform

  STAGE(0, 0);
  STAGE(1, 1);

#pragma unroll
  for (int c = 0; c < CPG; ++c) {
    // Per-wave counted waits (NO barrier -- buffers are wave-private).
    // FIFO after S(c): [st(c-2)], S(c+1):3, [st(c-1)] -> leave 5 in steady.
    if (c == 0)
      asm volatile("s_waitcnt vmcnt(3)" ::: "memory");
    else if (c == 1)
      asm volatile("s_waitcnt vmcnt(4)" ::: "memory");
    else if (c == CPG - 1)
      asm volatile("s_waitcnt vmcnt(2)" ::: "memory");
    else
      asm volatile("s_waitcnt vmcnt(5)" ::: "memory");

    // Prefetch 2 channels ahead into the slot this wave freed at iter c-1.
    if (c + 2 < CPG) STAGE(c + 2, (c + 2) % NBUF);

    const int bb = (c % NBUF) * BUFW + wb;
    const float* rA = hasUp ? &smem[bb] + w4 : &smem[ZROW] + w4;          // h-1
    const float* rB = &smem[bb + W_] + w4;                                // h
    const float* rC = hasDn ? &smem[bb + 2 * W_] + w4 : &smem[ZROW] + w4; // h+1

    float4 f0 = *(const float4*)rA;
    float4 f1 = *(const float4*)rB;
    float4 f2 = *(const float4*)rC;

    // w-halos via wave shuffles (wave spans the full row; lane edges = image edges)
    float l0 = __shfl_up(f0.w, 1),  l1 = __shfl_up(f1.w, 1),  l2 = __shfl_up(f2.w, 1);
    float r0 = __shfl_down(f0.x, 1), r1 = __shfl_down(f1.x, 1), r2 = __shfl_down(f2.x, 1);
    if (tx == 0)  { l0 = 0.f; l1 = 0.f; l2 = 0.f; }
    if (tx == 63) { r0 = 0.f; r1 = 0.f; r2 = 0.f; }

    float4 acc = f1;                     // residual: out = feat + FAC
    acc.x += l0   * a[0].x + f0.x * a[1].x + f0.y * a[2].x;
    acc.y += f0.x * a[0].y + f0.y * a[1].y + f0.z * a[2].y;
    acc.z += f0.y * a[0].z + f0.z * a[1].z + f0.w * a[2].z;
    acc.w += f0.z * a[0].w + f0.w * a[1].w + r0   * a[2].w;

    acc.x += l1   * a[3].x + f1.x * a[4].x + f1.y * a[5].x;
    acc.y += f1.x * a[3].y + f1.y * a[4].y + f1.z * a[5].y;
    acc.z += f1.y * a[3].z + f1.z * a[4].z + f1.w * a[5].z;
    acc.w += f1.z * a[3].w + f1.w * a[4].w + r1   * a[5].w;

    acc.x += l2   * a[6].x + f2.x * a[7].x + f2.y * a[8].x;
    acc.y += f2.x * a[6].y + f2.y * a[7].y + f2.z * a[8].y;
    acc.z += f2.y * a[6].z + f2.z * a[7].z + f2.w * a[8].z;
    acc.w += f2.z * a[6].w + f2.w * a[7].w + r2   * a[8].w;

    // Output is never re-read: nontemporal store keeps L2/L3 for the inputs.
    f32x4 accv = {acc.x, acc.y, acc.z, acc.w};
    __builtin_nontemporal_store(accv, (f32x4*)(obase + (size_t)c * plane));
  }
}

extern "C" void kernel_launch(void* const* d_in, const int* in_sizes, int n_in,
                              void* d_out, int out_size, void* d_ws, size_t ws_size,
                              hipStream_t stream) {
  const float* feat = (const float*)d_in[0];
  const float* att  = (const float*)d_in[1];
  float* out        = (float*)d_out;
  fac_kernel<<<NWG, 256, 0, stream>>>(feat, att, out);
}